// Round 5
// baseline (297.231 us; speedup 1.0000x reference)
//
#include <hip/hip_runtime.h>
#include <cstdint>
#include <cstddef>

namespace {
constexpr int Bn = 8, Dn = 512, Hn = 96, Wn = 96, HWn = Hn * Wn; // 9216
constexpr int Cn = 8, Kn = 10, CKn = Cn * Kn;                    // 80
constexpr int NPIX = Bn * HWn;                                   // 73728
constexpr int NCHUNK = 4, DCH = Dn / NCHUNK;                     // 4 x 128
constexpr int NMOM = 66;                                         // vm, 10 S_k, 55 S_kl
constexpr float EPSF = 1e-8f;
constexpr float MINM = 0.05f;
// fused-pool tiling: 4 output rows per (bc, tile); 10 staged hpool rows.
// LDS 43.3 KB -> 3 blocks/CU (12 waves/CU) vs HT=8's 60.2 KB / 2 blocks.
constexpr int HT = 4, HROWS = HT + 6, NTILE = Hn / HT;           // 4, 10, 24

// workspace layout (floats) — numH/denH eliminated by the fused pool kernel
constexpr size_t oPnT  = 0;                                    // [D][CK] 40960
constexpr size_t oS    = oPnT + (size_t)Dn * CKn;              // [B][K][HW] 737280
constexpr size_t oPart = oS + (size_t)Bn * Kn * HWn;           // [chunk][11][NPIX] 3244032
constexpr size_t oMom  = oPart + (size_t)NCHUNK * 11 * NPIX;   // [BC][66] 4224 (zeroed by K0)
constexpr size_t oCnt  = oMom + 64 * NMOM;                     // [BC] int 64  (zeroed by K0)
constexpr size_t oEnd  = oCnt + 64;
constexpr int    ZERO_WORDS = 64 * NMOM + 64;                  // words zeroed by K0
} // namespace

__device__ __forceinline__ float wred64(float v) {
#pragma unroll
    for (int o = 32; o > 0; o >>= 1) v += __shfl_down(v, o, 64);
    return v;
}

// ---------------------------------------------------------------------------
// K0: normalize prototypes, store transposed PnT[d][ck].
// Block 0 additionally zeroes mom/cnt (replaces the hipMemsetAsync node;
// stream order guarantees completion before k_simred/k_pool atomics).
__global__ __launch_bounds__(64) void k_protonorm(const float* __restrict__ P,
                                                  float* __restrict__ PnT,
                                                  float* __restrict__ zero_base) {
    int ck = blockIdx.x, lane = threadIdx.x;
    if (ck == 0) {
        for (int i = lane; i < ZERO_WORDS; i += 64) zero_base[i] = 0.0f;
    }
    float v[8]; float ss = 0.f;
#pragma unroll
    for (int j = 0; j < 8; ++j) { v[j] = P[ck * Dn + lane + 64 * j]; ss += v[j] * v[j]; }
    ss = wred64(ss);
    ss = __shfl(ss, 0, 64);
    float inv = 1.0f / fmaxf(sqrtf(ss), 1e-12f);
#pragma unroll
    for (int j = 0; j < 8; ++j)
        PnT[(size_t)(lane + 64 * j) * CKn + ck] = v[j] * inv;
}

// ---------------------------------------------------------------------------
// K1: split-D partial sims. grid (288 pixel-blocks, 4 d-chunks).
__global__ __launch_bounds__(256) void k_sim(const float* __restrict__ F,
                                             const float* __restrict__ PnT,
                                             const int* __restrict__ mask,
                                             float* __restrict__ part) {
    __shared__ alignas(16) float pch[64 * 96]; // [dd][c*12+k], padded, 24.6 KB
    const int tid = threadIdx.x;
    const int pix = blockIdx.x * 256 + tid;
    const int chunk = blockIdx.y;
    const int b = pix / HWn, hw = pix % HWn;

    const int m = mask[pix];
    const int cc = m > 0 ? m - 1 : 0;

    float acc[Kn]; float ss = 0.f;
#pragma unroll
    for (int k = 0; k < Kn; ++k) acc[k] = 0.f;

    for (int p = 0; p < DCH / 64; ++p) {
        const int dbase = chunk * DCH + p * 64;
        __syncthreads();
        for (int i = tid; i < 64 * CKn; i += 256) {
            int dd = i / CKn, ck = i % CKn;
            int c = ck / Kn, kk = ck % Kn;
            pch[dd * 96 + c * 12 + kk] = PnT[(size_t)(dbase + dd) * CKn + ck];
        }
        __syncthreads();
#pragma unroll 4
        for (int dd = 0; dd < 64; ++dd) {
            float f = F[(size_t)(b * Dn + dbase + dd) * HWn + hw];
            ss += f * f;
            const float4* p4 = (const float4*)&pch[dd * 96 + cc * 12];
            float4 pa = p4[0], pb = p4[1];
            float2 pc = *(const float2*)&pch[dd * 96 + cc * 12 + 8];
            acc[0] += f * pa.x; acc[1] += f * pa.y; acc[2] += f * pa.z; acc[3] += f * pa.w;
            acc[4] += f * pb.x; acc[5] += f * pb.y; acc[6] += f * pb.z; acc[7] += f * pb.w;
            acc[8] += f * pc.x; acc[9] += f * pc.y;
        }
    }
#pragma unroll
    for (int k = 0; k < Kn; ++k)
        part[(size_t)(chunk * 11 + k) * NPIX + pix] = acc[k];
    part[(size_t)(chunk * 11 + 10) * NPIX + pix] = ss;
}

// ---------------------------------------------------------------------------
// K2: reduce chunks, normalize, write S[b][k][hw]; class histogram.
__global__ __launch_bounds__(256) void k_simred(const float* __restrict__ part,
                                                const int* __restrict__ mask,
                                                float* __restrict__ S,
                                                int* __restrict__ cnt) {
    __shared__ int hist[Cn];
    const int tid = threadIdx.x;
    const int pix = blockIdx.x * 256 + tid;
    if (tid < Cn) hist[tid] = 0;
    __syncthreads();

    float acc[Kn]; float ss = 0.f;
#pragma unroll
    for (int k = 0; k < Kn; ++k) acc[k] = 0.f;
#pragma unroll
    for (int ch = 0; ch < NCHUNK; ++ch) {
#pragma unroll
        for (int k = 0; k < Kn; ++k)
            acc[k] += part[(size_t)(ch * 11 + k) * NPIX + pix];
        ss += part[(size_t)(ch * 11 + 10) * NPIX + pix];
    }
    float inv = 1.0f / fmaxf(sqrtf(ss), 1e-12f);
    const int b = pix / HWn, hw = pix % HWn;
#pragma unroll
    for (int k = 0; k < Kn; ++k)
        S[(size_t)(b * Kn + k) * HWn + hw] = acc[k] * inv;

    const int m = mask[pix];
    if (m > 0) atomicAdd(&hist[m - 1], 1);
    __syncthreads();
    if (tid < Cn) atomicAdd(&cnt[(pix / HWn) * Cn + tid], hist[tid]);
}

// ---------------------------------------------------------------------------
// K3 (fused hpool+vpool): one block per (bc, 4-row band). Horizontal 7-window
// sums (ascending-column order) land in LDS; after a barrier the vertical
// 7-window sums + raw moments (ascending-row order) are computed from LDS.
// HT=4: 43.3 KB LDS -> 3 blocks/CU; 1536 blocks.
__global__ __launch_bounds__(256) void k_pool(const int* __restrict__ mask,
                                              const float* __restrict__ S,
                                              float* __restrict__ mom) {
    __shared__ alignas(16) float hp[Kn][HROWS][Wn];  // 38.4 KB
    __shared__ alignas(16) float hd[HROWS][Wn];      //  3.84 KB
    __shared__ alignas(16) float red[4][NMOM];       //  1.03 KB

    const int tid = threadIdx.x;
    const int ht = blockIdx.x % NTILE;
    const int bc = blockIdx.x / NTILE;
    const int c = bc & 7, b = bc >> 3;
    const int h0 = ht * HT;

    // ---- horizontal phase: units = (k-pair, staged row, w-group-of-4) ----
    // 5 * 10 * 24 = 1200 units; columns w0-3..w0+6 loaded once, added into the
    // (up to 4) outputs whose window covers them — ascending-column order.
    for (int u = tid; u < 5 * HROWS * 24; u += 256) {
        const int wg = u % 24;
        int r = u / 24;
        const int row = r % HROWS;
        const int k2 = r / HROWS;
        const int hh = h0 - 3 + row;
        if (hh < 0 || hh >= Hn) continue;
        const int k0 = 2 * k2;
        const int w0 = wg * 4;
        const int rowb = b * HWn + hh * Wn;
        const float* S0 = &S[(size_t)(b * Kn + k0) * HWn + hh * Wn];
        const float* S1 = S0 + HWn;

        float a0[4] = {0.f, 0.f, 0.f, 0.f};
        float a1[4] = {0.f, 0.f, 0.f, 0.f};
        float dn[4] = {0.f, 0.f, 0.f, 0.f};
#pragma unroll
        for (int dc = -3; dc <= 6; ++dc) {
            int ww = w0 + dc;
            if (ww < 0 || ww >= Wn) continue;
            float hv = (mask[rowb + ww] == c + 1) ? 1.0f : 0.0f;
            float s0 = S0[ww] * hv;
            float s1 = S1[ww] * hv;
            const int olo = dc - 3 > 0 ? dc - 3 : 0;
            const int ohi = dc + 3 < 3 ? dc + 3 : 3;
#pragma unroll
            for (int o = 0; o < 4; ++o) {
                if (o < olo || o > ohi) continue;
                a0[o] += s0; a1[o] += s1; dn[o] += hv;
            }
        }
#pragma unroll
        for (int o = 0; o < 4; ++o) {
            hp[k0][row][w0 + o]     = a0[o];
            hp[k0 + 1][row][w0 + o] = a1[o];
        }
        if (k2 == 0) {
#pragma unroll
            for (int o = 0; o < 4; ++o) hd[row][w0 + o] = dn[o];
        }
    }
    __syncthreads();

    // ---- vertical phase + moments: 4*96 = 384 output pixels ----
    float m[NMOM];
#pragma unroll
    for (int i = 0; i < NMOM; ++i) m[i] = 0.f;

    for (int idx = tid; idx < HT * Wn; idx += 256) {
        const int w = idx % Wn;
        const int oh = idx / Wn;
        const int h = h0 + oh;

        float dacc = 0.f;
        float nacc[Kn];
#pragma unroll
        for (int k = 0; k < Kn; ++k) nacc[k] = 0.f;
#pragma unroll
        for (int dr = -3; dr <= 3; ++dr) {
            const int hh = h + dr;
            if (hh < 0 || hh >= Hn) continue;
            const int row = hh - h0 + 3;     // 0..HROWS-1
            dacc += hd[row][w];
#pragma unroll
            for (int k = 0; k < Kn; ++k) nacc[k] += hp[k][row][w];
        }

        const float dA = dacc * (1.0f / 49.0f);
        const float inv = 1.0f / (dA + EPSF);
        const float vm = (dA > MINM) ? 1.0f : 0.0f;
        float rr[Kn];
#pragma unroll
        for (int k = 0; k < Kn; ++k)
            rr[k] = nacc[k] * (1.0f / 49.0f) * inv * vm; // pre-masked
        m[0] += vm;
#pragma unroll
        for (int k = 0; k < Kn; ++k) m[1 + k] += rr[k];
        int p = 11;
#pragma unroll
        for (int k = 0; k < Kn; ++k)
#pragma unroll
            for (int l = 0; l <= k; ++l, ++p) m[p] += rr[k] * rr[l];
    }

    // block-reduce 66 moments
    const int lane = tid & 63, wv = tid >> 6;
#pragma unroll
    for (int i = 0; i < NMOM; ++i) {
        float x = wred64(m[i]);
        if (lane == 0) red[wv][i] = x;
    }
    __syncthreads();
    for (int i = tid; i < NMOM; i += 256)
        atomicAdd(&mom[bc * NMOM + i],
                  red[0][i] + red[1][i] + red[2][i] + red[3][i]);
}

// ---------------------------------------------------------------------------
// K5: finalize from raw moments: M[kl] = S_kl - S_k S_l / Vf, loss, scalar
__global__ __launch_bounds__(64) void k_final(const float* __restrict__ mom,
                                              const int* __restrict__ cnt,
                                              float* __restrict__ out) {
    const int bc = threadIdx.x; // 0..63
    float mo[NMOM];
#pragma unroll
    for (int i = 0; i < NMOM; ++i) mo[i] = mom[bc * NMOM + i];
    const float V = mo[0];
    const float Vf = fmaxf(V, 1.0f);
    float Sk[Kn];
#pragma unroll
    for (int k = 0; k < Kn; ++k) Sk[k] = mo[1 + k];

    float M[55];
    {
        int p = 0;
#pragma unroll
        for (int k = 0; k < Kn; ++k)
#pragma unroll
            for (int l = 0; l <= k; ++l, ++p)
                M[p] = mo[11 + p] - Sk[k] * Sk[l] / Vf;
    }
    float nrm[Kn];
#pragma unroll
    for (int k = 0; k < Kn; ++k)
        nrm[k] = sqrtf(fmaxf(M[k * (k + 1) / 2 + k], 0.0f));
    float loss = 0.f;
    {
        int p = 0;
#pragma unroll
        for (int k = 0; k < Kn; ++k) {
#pragma unroll
            for (int l = 0; l <= k; ++l, ++p) {
                if (l == k) continue;
                float g = M[p] / ((nrm[k] + EPSF) * (nrm[l] + EPSF)) / Vf;
                loss += 2.0f * g * g;
            }
        }
    }
    loss *= 1.0f / (float)(Kn * (Kn - 1));
    bool act = (cnt[bc] >= 1) && (V >= 2.0f);
    float sl = act ? loss : 0.f;
    float sa = act ? 1.f : 0.f;
#pragma unroll
    for (int o = 4; o > 0; o >>= 1) {
        sl += __shfl_down(sl, o, 8);
        sa += __shfl_down(sa, o, 8);
    }
    __shared__ float pimg[Bn];
    if ((bc & 7) == 0) pimg[bc >> 3] = sl / fmaxf(sa, 1.0f);
    __syncthreads();
    if (bc == 0) {
        float tot = 0.f;
#pragma unroll
        for (int b = 0; b < Bn; ++b) tot += pimg[b];
        out[0] = tot / (float)Bn;
    }
}

// ---------------------------------------------------------------------------
extern "C" void kernel_launch(void* const* d_in, const int* in_sizes, int n_in,
                              void* d_out, int out_size, void* d_ws, size_t ws_size,
                              hipStream_t stream) {
    const float* F  = (const float*)d_in[0];
    const float* P  = (const float*)d_in[1];
    const int* mask = (const int*)d_in[2];
    float* ws = (float*)d_ws;
    float* out = (float*)d_out;

    k_protonorm<<<CKn, 64, 0, stream>>>(P, ws + oPnT, ws + oMom);
    k_sim<<<dim3(NPIX / 256, NCHUNK), 256, 0, stream>>>(F, ws + oPnT, mask, ws + oPart);
    k_simred<<<NPIX / 256, 256, 0, stream>>>(ws + oPart, mask, ws + oS, (int*)(ws + oCnt));
    k_pool<<<64 * NTILE, 256, 0, stream>>>(mask, ws + oS, ws + oMom);
    k_final<<<1, 64, 0, stream>>>(ws + oMom, (const int*)(ws + oCnt), out);
}

// Round 6
// 285.584 us; speedup vs baseline: 1.0408x; 1.0408x over previous
//
#include <hip/hip_runtime.h>
#include <cstdint>
#include <cstddef>

namespace {
constexpr int Bn = 8, Dn = 512, Hn = 96, Wn = 96, HWn = Hn * Wn; // 9216
constexpr int Cn = 8, Kn = 10, CKn = Cn * Kn;                    // 80
constexpr int NPIX = Bn * HWn;                                   // 73728
constexpr int NCHUNK = 4, DCH = Dn / NCHUNK;                     // 4 x 128
constexpr int NMOM = 66;                                         // vm, 10 S_k, 55 S_kl
constexpr float EPSF = 1e-8f;
constexpr float MINM = 0.05f;

// workspace layout (floats)
constexpr size_t oPnT  = 0;                                    // [D][CK] 40960
constexpr size_t oS    = oPnT + (size_t)Dn * CKn;              // [B][K][HW] 737280
constexpr size_t oNumH = oS + (size_t)Bn * Kn * HWn;           // [BC][K][HW] 5898240
constexpr size_t oPart = oNumH;                                // alias: [chunk][11][NPIX] (consumed before numH written)
constexpr size_t oDenH = oNumH + (size_t)Bn * Cn * Kn * HWn;   // [BC][HW] 589824
constexpr size_t oMom  = oDenH + (size_t)Bn * Cn * HWn;        // [BC][66] 4224 (zeroed)
constexpr size_t oCnt  = oMom + 64 * NMOM;                     // [BC] int 64  (zeroed)
constexpr size_t oEnd  = oCnt + 64;
} // namespace

__device__ __forceinline__ float wred64(float v) {
#pragma unroll
    for (int o = 32; o > 0; o >>= 1) v += __shfl_down(v, o, 64);
    return v;
}

// ---------------------------------------------------------------------------
// K0: normalize prototypes, store transposed PnT[d][ck]
__global__ __launch_bounds__(64) void k_protonorm(const float* __restrict__ P,
                                                  float* __restrict__ PnT) {
    int ck = blockIdx.x, lane = threadIdx.x;
    float v[8]; float ss = 0.f;
#pragma unroll
    for (int j = 0; j < 8; ++j) { v[j] = P[ck * Dn + lane + 64 * j]; ss += v[j] * v[j]; }
    ss = wred64(ss);
    ss = __shfl(ss, 0, 64);
    float inv = 1.0f / fmaxf(sqrtf(ss), 1e-12f);
#pragma unroll
    for (int j = 0; j < 8; ++j)
        PnT[(size_t)(lane + 64 * j) * CKn + ck] = v[j] * inv;
}

// ---------------------------------------------------------------------------
// K1: split-D partial sims. grid (288 pixel-blocks, 4 d-chunks).
__global__ __launch_bounds__(256) void k_sim(const float* __restrict__ F,
                                             const float* __restrict__ PnT,
                                             const int* __restrict__ mask,
                                             float* __restrict__ part) {
    __shared__ float pch[64 * 96]; // [dd][c*12+k], padded, 24.6 KB
    const int tid = threadIdx.x;
    const int pix = blockIdx.x * 256 + tid;
    const int chunk = blockIdx.y;
    const int b = pix / HWn, hw = pix % HWn;

    const int m = mask[pix];
    const int cc = m > 0 ? m - 1 : 0;

    float acc[Kn]; float ss = 0.f;
#pragma unroll
    for (int k = 0; k < Kn; ++k) acc[k] = 0.f;

    for (int p = 0; p < DCH / 64; ++p) {
        const int dbase = chunk * DCH + p * 64;
        __syncthreads();
        for (int i = tid; i < 64 * CKn; i += 256) {
            int dd = i / CKn, ck = i % CKn;
            int c = ck / Kn, kk = ck % Kn;
            pch[dd * 96 + c * 12 + kk] = PnT[(size_t)(dbase + dd) * CKn + ck];
        }
        __syncthreads();
#pragma unroll 4
        for (int dd = 0; dd < 64; ++dd) {
            float f = F[(size_t)(b * Dn + dbase + dd) * HWn + hw];
            ss += f * f;
            const float4* p4 = (const float4*)&pch[dd * 96 + cc * 12];
            float4 pa = p4[0], pb = p4[1];
            float2 pc = *(const float2*)&pch[dd * 96 + cc * 12 + 8];
            acc[0] += f * pa.x; acc[1] += f * pa.y; acc[2] += f * pa.z; acc[3] += f * pa.w;
            acc[4] += f * pb.x; acc[5] += f * pb.y; acc[6] += f * pb.z; acc[7] += f * pb.w;
            acc[8] += f * pc.x; acc[9] += f * pc.y;
        }
    }
#pragma unroll
    for (int k = 0; k < Kn; ++k)
        part[(size_t)(chunk * 11 + k) * NPIX + pix] = acc[k];
    part[(size_t)(chunk * 11 + 10) * NPIX + pix] = ss;
}

// ---------------------------------------------------------------------------
// K2: reduce chunks, normalize, write S[b][k][hw]; class histogram.
__global__ __launch_bounds__(256) void k_simred(const float* __restrict__ part,
                                                const int* __restrict__ mask,
                                                float* __restrict__ S,
                                                int* __restrict__ cnt) {
    __shared__ int hist[Cn];
    const int tid = threadIdx.x;
    const int pix = blockIdx.x * 256 + tid;
    if (tid < Cn) hist[tid] = 0;
    __syncthreads();

    float acc[Kn]; float ss = 0.f;
#pragma unroll
    for (int k = 0; k < Kn; ++k) acc[k] = 0.f;
#pragma unroll
    for (int ch = 0; ch < NCHUNK; ++ch) {
#pragma unroll
        for (int k = 0; k < Kn; ++k)
            acc[k] += part[(size_t)(ch * 11 + k) * NPIX + pix];
        ss += part[(size_t)(ch * 11 + 10) * NPIX + pix];
    }
    float inv = 1.0f / fmaxf(sqrtf(ss), 1e-12f);
    const int b = pix / HWn, hw = pix % HWn;
#pragma unroll
    for (int k = 0; k < Kn; ++k)
        S[(size_t)(b * Kn + k) * HWn + hw] = acc[k] * inv;

    const int m = mask[pix];
    if (m > 0) atomicAdd(&hist[m - 1], 1);
    __syncthreads();
    if (tid < Cn) atomicAdd(&cnt[(pix / HWn) * Cn + tid], hist[tid]);
}

// ---------------------------------------------------------------------------
// K3: horizontal 7-pool; thread per (bc, k-pair, h, w-group-of-4).
// Columns w0-3..w0+6 are loaded once and added into the (up to 4) outputs
// whose window covers them — ascending-column order, bit-identical sums.
__global__ __launch_bounds__(256) void k_hpool(const int* __restrict__ mask,
                                               const float* __restrict__ S,
                                               float* __restrict__ numH,
                                               float* __restrict__ denH) {
    const int t = blockIdx.x * 256 + threadIdx.x; // ((bc*5+k2)*96+h)*24+wg
    const int wg = t % 24;
    int r = t / 24;
    const int h = r % Hn; r /= Hn;
    const int k2 = r % 5;
    const int bc = r / 5;
    const int c = bc & 7, b = bc >> 3;
    const int k0 = 2 * k2;
    const int w0 = wg * 4;
    const int rowb = b * HWn + h * Wn;
    const float* S0 = &S[(size_t)(b * Kn + k0) * HWn + h * Wn];
    const float* S1 = &S[(size_t)(b * Kn + k0 + 1) * HWn + h * Wn];

    float a0[4] = {0.f, 0.f, 0.f, 0.f};
    float a1[4] = {0.f, 0.f, 0.f, 0.f};
    float dn[4] = {0.f, 0.f, 0.f, 0.f};

#pragma unroll
    for (int dc = -3; dc <= 6; ++dc) {
        int ww = w0 + dc;
        if (ww < 0 || ww >= Wn) continue;
        float hv = (mask[rowb + ww] == c + 1) ? 1.0f : 0.0f;
        float s0 = S0[ww] * hv;
        float s1 = S1[ww] * hv;
        const int olo = dc - 3 > 0 ? dc - 3 : 0;
        const int ohi = dc + 3 < 3 ? dc + 3 : 3;
#pragma unroll
        for (int o = 0; o < 4; ++o) {
            if (o < olo || o > ohi) continue;
            a0[o] += s0; a1[o] += s1; dn[o] += hv;
        }
    }
    float4* n0 = (float4*)&numH[(size_t)(bc * Kn + k0) * HWn + h * Wn + w0];
    float4* n1 = (float4*)&numH[(size_t)(bc * Kn + k0 + 1) * HWn + h * Wn + w0];
    *n0 = make_float4(a0[0], a0[1], a0[2], a0[3]);
    *n1 = make_float4(a1[0], a1[1], a1[2], a1[3]);
    if (k2 == 0)
        *(float4*)&denH[(size_t)bc * HWn + h * Wn + w0] =
            make_float4(dn[0], dn[1], dn[2], dn[3]);
}

// ---------------------------------------------------------------------------
// K4: vertical 7-pool, 4 outputs/thread along H (rows h0-3..h0+6 loaded once,
// shared across the 4 overlapping windows); thread-local raw moments, one
// 66-way block reduction, atomics into mom[bc][66].
__global__ __launch_bounds__(256) void k_vpool(const float* __restrict__ numH,
                                               const float* __restrict__ denH,
                                               float* __restrict__ mom) {
    const int t = blockIdx.x * 256 + threadIdx.x; // (bc*24+hg)*96+w
    const int w = t % Wn;
    int r = t / Wn;
    const int hg = r % 24;
    const int bc = r / 24;
    const int h0 = hg * 4;

    float nacc[4][Kn];
    float dacc[4] = {0.f, 0.f, 0.f, 0.f};
#pragma unroll
    for (int o = 0; o < 4; ++o)
#pragma unroll
        for (int k = 0; k < Kn; ++k) nacc[o][k] = 0.f;

#pragma unroll
    for (int dr = -3; dr <= 6; ++dr) {
        int hh = h0 + dr;
        if (hh < 0 || hh >= Hn) continue;
        const int olo = dr - 3 > 0 ? dr - 3 : 0;
        const int ohi = dr + 3 < 3 ? dr + 3 : 3;
        float dv = denH[(size_t)bc * HWn + hh * Wn + w];
#pragma unroll
        for (int o = 0; o < 4; ++o) {
            if (o < olo || o > ohi) continue;
            dacc[o] += dv;
        }
#pragma unroll
        for (int k = 0; k < Kn; ++k) {
            float nv = numH[(size_t)(bc * Kn + k) * HWn + hh * Wn + w];
#pragma unroll
            for (int o = 0; o < 4; ++o) {
                if (o < olo || o > ohi) continue;
                nacc[o][k] += nv;
            }
        }
    }

    // thread-local moments over the 4 output pixels
    float m[NMOM];
#pragma unroll
    for (int i = 0; i < NMOM; ++i) m[i] = 0.f;
#pragma unroll
    for (int o = 0; o < 4; ++o) {
        float dA = dacc[o] * (1.0f / 49.0f);
        float inv = 1.0f / (dA + EPSF);
        float vm = (dA > MINM) ? 1.0f : 0.0f;
        float rr[Kn];
#pragma unroll
        for (int k = 0; k < Kn; ++k)
            rr[k] = nacc[o][k] * (1.0f / 49.0f) * inv * vm; // pre-masked
        m[0] += vm;
#pragma unroll
        for (int k = 0; k < Kn; ++k) m[1 + k] += rr[k];
        int p = 11;
#pragma unroll
        for (int k = 0; k < Kn; ++k)
#pragma unroll
            for (int l = 0; l <= k; ++l, ++p) m[p] += rr[k] * rr[l];
    }

    // block-reduce 66 moments
    __shared__ float red[4][NMOM];
    const int lane = threadIdx.x & 63, wv = threadIdx.x >> 6;
#pragma unroll
    for (int i = 0; i < NMOM; ++i) {
        float x = wred64(m[i]);
        if (lane == 0) red[wv][i] = x;
    }
    __syncthreads();
    for (int i = threadIdx.x; i < NMOM; i += 256)
        atomicAdd(&mom[bc * NMOM + i],
                  red[0][i] + red[1][i] + red[2][i] + red[3][i]);
}

// ---------------------------------------------------------------------------
// K5: finalize from raw moments: M[kl] = S_kl - S_k S_l / Vf, loss, scalar
__global__ __launch_bounds__(64) void k_final(const float* __restrict__ mom,
                                              const int* __restrict__ cnt,
                                              float* __restrict__ out) {
    const int bc = threadIdx.x; // 0..63
    float mo[NMOM];
#pragma unroll
    for (int i = 0; i < NMOM; ++i) mo[i] = mom[bc * NMOM + i];
    const float V = mo[0];
    const float Vf = fmaxf(V, 1.0f);
    float Sk[Kn];
#pragma unroll
    for (int k = 0; k < Kn; ++k) Sk[k] = mo[1 + k];

    float M[55];
    {
        int p = 0;
#pragma unroll
        for (int k = 0; k < Kn; ++k)
#pragma unroll
            for (int l = 0; l <= k; ++l, ++p)
                M[p] = mo[11 + p] - Sk[k] * Sk[l] / Vf;
    }
    float nrm[Kn];
#pragma unroll
    for (int k = 0; k < Kn; ++k)
        nrm[k] = sqrtf(fmaxf(M[k * (k + 1) / 2 + k], 0.0f));
    float loss = 0.f;
    {
        int p = 0;
#pragma unroll
        for (int k = 0; k < Kn; ++k) {
#pragma unroll
            for (int l = 0; l <= k; ++l, ++p) {
                if (l == k) continue;
                float g = M[p] / ((nrm[k] + EPSF) * (nrm[l] + EPSF)) / Vf;
                loss += 2.0f * g * g;
            }
        }
    }
    loss *= 1.0f / (float)(Kn * (Kn - 1));
    bool act = (cnt[bc] >= 1) && (V >= 2.0f);
    float sl = act ? loss : 0.f;
    float sa = act ? 1.f : 0.f;
#pragma unroll
    for (int o = 4; o > 0; o >>= 1) {
        sl += __shfl_down(sl, o, 8);
        sa += __shfl_down(sa, o, 8);
    }
    __shared__ float pimg[Bn];
    if ((bc & 7) == 0) pimg[bc >> 3] = sl / fmaxf(sa, 1.0f);
    __syncthreads();
    if (bc == 0) {
        float tot = 0.f;
#pragma unroll
        for (int b = 0; b < Bn; ++b) tot += pimg[b];
        out[0] = tot / (float)Bn;
    }
}

// ---------------------------------------------------------------------------
extern "C" void kernel_launch(void* const* d_in, const int* in_sizes, int n_in,
                              void* d_out, int out_size, void* d_ws, size_t ws_size,
                              hipStream_t stream) {
    const float* F  = (const float*)d_in[0];
    const float* P  = (const float*)d_in[1];
    const int* mask = (const int*)d_in[2];
    float* ws = (float*)d_ws;
    float* out = (float*)d_out;

    hipMemsetAsync(ws + oMom, 0, (oEnd - oMom) * sizeof(float), stream);

    k_protonorm<<<CKn, 64, 0, stream>>>(P, ws + oPnT);
    k_sim<<<dim3(NPIX / 256, NCHUNK), 256, 0, stream>>>(F, ws + oPnT, mask, ws + oPart);
    k_simred<<<NPIX / 256, 256, 0, stream>>>(ws + oPart, mask, ws + oS, (int*)(ws + oCnt));
    k_hpool<<<Bn * Cn * 5 * Hn * 24 / 256, 256, 0, stream>>>(mask, ws + oS,
                                                             ws + oNumH, ws + oDenH);
    k_vpool<<<Bn * Cn * 24 * Wn / 256, 256, 0, stream>>>(ws + oNumH, ws + oDenH, ws + oMom);
    k_final<<<1, 64, 0, stream>>>(ws + oMom, (const int*)(ws + oCnt), out);
}